// Round 3
// baseline (676.957 us; speedup 1.0000x reference)
//
#include <hip/hip_runtime.h>
#include <hip/hip_bf16.h>
#include <cmath>

using short8  = __attribute__((ext_vector_type(8))) short;
using f32x16  = __attribute__((ext_vector_type(16))) float;

#define MFMA32B(a,b,c) __builtin_amdgcn_mfma_f32_32x32x16_bf16(a, b, c, 0, 0, 0)
#define MFMA32F8(a,b,c) __builtin_amdgcn_mfma_f32_32x32x16_fp8_fp8(a, b, c, 0, 0, 0)

__device__ __forceinline__ unsigned short f2bf(float f) {
    union { float f; unsigned u; } v; v.f = f;
    unsigned u = v.u;
    return (unsigned short)((u + 0x7FFFu + ((u >> 16) & 1u)) >> 16);  // RNE
}
__device__ __forceinline__ float bf2f(unsigned short h) {
    union { unsigned u; float f; } v; v.u = ((unsigned)h) << 16;
    return v.f;
}
__device__ __forceinline__ float softplus(float x) {
    return fmaxf(x, 0.f) + log1pf(expf(-fabsf(x)));  // stable
}
__device__ __forceinline__ unsigned f4_to_fp8x4(float4 f) {
    int v = __builtin_amdgcn_cvt_pk_fp8_f32(f.x, f.y, 0, false);
    v = __builtin_amdgcn_cvt_pk_fp8_f32(f.z, f.w, v, true);
    return (unsigned)v;
}
__device__ __forceinline__ unsigned char f_to_fp8(float f) {
    return (unsigned char)(__builtin_amdgcn_cvt_pk_fp8_f32(f, f, 0, false) & 0xFF);
}

// ---- bf16 B-fragment pack (32x32x16): m = ct*32+(lane&31), k = kk*16+(lane>>5)*8+j ----
__global__ void pack_w_bf16(const float* __restrict__ W, unsigned short* __restrict__ out,
                            int K_real, int M_real, int KT, int CT) {
    int tid = blockIdx.x * blockDim.x + threadIdx.x;
    if (tid >= CT * KT * 64) return;
    int lane = tid & 63;
    int t    = tid >> 6;
    int kk   = t % KT;
    int ct   = t / KT;
    int m  = ct * 32 + (lane & 31);
    int k0 = kk * 16 + ((lane >> 5) << 3);
    short8 v;
#pragma unroll
    for (int j = 0; j < 8; ++j) {
        int k = k0 + j;
        float f = (k < K_real && m < M_real) ? W[(size_t)k * M_real + m] : 0.f;
        v[j] = (short)f2bf(f);
    }
    *(((short8*)out) + tid) = v;
}

// ---- fp8 B-fragment pack (32x32x16 fp8): 8 bytes/lane, same k-map ----
__global__ void pack_w_fp8(const float* __restrict__ W, unsigned long long* __restrict__ out,
                           int K_real, int M_real, int KT, int CT) {
    int tid = blockIdx.x * blockDim.x + threadIdx.x;
    if (tid >= CT * KT * 64) return;
    int lane = tid & 63;
    int t    = tid >> 6;
    int kk   = t % KT;
    int ct   = t / KT;
    int m  = ct * 32 + (lane & 31);
    int k0 = kk * 16 + ((lane >> 5) << 3);
    float f[8];
#pragma unroll
    for (int j = 0; j < 8; ++j) {
        int k = k0 + j;
        f[j] = (k < K_real && m < M_real) ? W[(size_t)k * M_real + m] : 0.f;
    }
    unsigned lo = (unsigned)__builtin_amdgcn_cvt_pk_fp8_f32(f[0], f[1], 0, false);
    lo = (unsigned)__builtin_amdgcn_cvt_pk_fp8_f32(f[2], f[3], (int)lo, true);
    unsigned hi = (unsigned)__builtin_amdgcn_cvt_pk_fp8_f32(f[4], f[5], 0, false);
    hi = (unsigned)__builtin_amdgcn_cvt_pk_fp8_f32(f[6], f[7], (int)hi, true);
    out[tid] = (unsigned long long)lo | ((unsigned long long)hi << 32);
}

// ---------------- fused MLP + loss partials ----------------
// BM=64 rows/block, 8 waves, 2 blocks/CU target (LDS 64KB, VGPR<=128).
// LDS byte layout (region reuse over time):
//   [0,32768)     : X fp8   64x512B  (swz ^=(row&15)<<3)  -> later h2 fp8 64x512B (same swz)
//   [32768,65536) : h1q bf16 64x256col (rowBytes 512, swz ^=(row&15)<<4)
//                   -> later h3 bf16 64x256col (same layout)
// L1 (fp8) fused with L2 (bf16) in 4 col-quarter slabs of h1; acc2 persists (64 VGPR).
// L3 (fp8) -> h3 -> L4 dot + stable BCE -> per-block partials.
__global__ __launch_bounds__(512, 4) void fused_mlp(
    const float* __restrict__ Xf, const float* __restrict__ Xr,
    const unsigned long long* __restrict__ pW1, const unsigned short* __restrict__ pW2,
    const unsigned long long* __restrict__ pW3,
    const float* __restrict__ b1, const float* __restrict__ b2,
    const float* __restrict__ b3, const float* __restrict__ W4,
    const float* __restrict__ b4, float* __restrict__ partials)
{
    __shared__ __align__(16) unsigned char smem[65536];
    __shared__ float red[128];

    const int tidx = threadIdx.x;
    const int wid  = tidx >> 6;
    const int lane = tidx & 63;
    const int l31  = lane & 31;
    const int hi   = lane >> 5;
    const int swz3 = (l31 & 15) << 3;   // row-swizzle for rows l31 and 32+l31 (same &15)
    const int swz4 = (l31 & 15) << 4;

    const long grow0 = (long)blockIdx.x * 64;   // blocks 0..1023 fake, 1024..2047 real
    const float* X = (grow0 < 65536) ? (Xf + (size_t)grow0 * 512)
                                     : (Xr + (size_t)(grow0 - 65536) * 512);

    // ---- stage X (fp32 HBM -> fp8 LDS), once, full K=512 ----
    {
        float4 xr[16];
#pragma unroll
        for (int it = 0; it < 16; ++it) {
            int idx = it * 512 + tidx; int r = idx >> 7; int c4 = (idx & 127) * 4;
            xr[it] = *(const float4*)(X + (size_t)r * 512 + c4);
        }
#pragma unroll
        for (int it = 0; it < 16; ++it) {
            int idx = it * 512 + tidx; int r = idx >> 7; int c4 = (idx & 127) * 4;
            *(unsigned*)(smem + r * 512 + (c4 ^ ((r & 15) << 3))) = f4_to_fp8x4(xr[it]);
        }
    }

    f32x16 acc2[2][2];
#pragma unroll
    for (int c = 0; c < 2; ++c)
#pragma unroll
        for (int rt = 0; rt < 2; ++rt)
#pragma unroll
            for (int rg = 0; rg < 16; ++rg) acc2[c][rt][rg] = 0.f;

    __syncthreads();

    for (int q = 0; q < 4; ++q) {
        // ======== L1 quarter: X[64x512] @ W1[:, q*256 .. q*256+256) (fp8) ========
        f32x16 acc1[2];
#pragma unroll
        for (int rt = 0; rt < 2; ++rt)
#pragma unroll
            for (int rg = 0; rg < 16; ++rg) acc1[rt][rg] = 0.f;

        const int ct1 = q * 8 + wid;    // this wave's 32-col tile (global ct)
        const unsigned long long* bp1 = pW1 + ((size_t)ct1 * 32) * 64 + lane;
#pragma unroll 8
        for (int kk = 0; kk < 32; ++kk) {
            int k0 = kk * 16 + hi * 8;
            long long a0 = *(const long long*)(smem + l31 * 512 + (k0 ^ swz3));
            long long a1 = *(const long long*)(smem + (32 + l31) * 512 + (k0 ^ swz3));
            long long b  = bp1[(size_t)kk * 64];
            acc1[0] = MFMA32F8(a0, b, acc1[0]);
            acc1[1] = MFMA32F8(a1, b, acc1[1]);
        }
        // epilogue: bias+relu -> h1q bf16 at [32768,65536), local col = wid*32+l31
        {
            int colq = wid * 32 + l31;
            int colg = q * 256 + colq;
            float bias = (colg < 1000) ? b1[colg] : 0.f;
#pragma unroll
            for (int rt = 0; rt < 2; ++rt)
#pragma unroll
                for (int rg = 0; rg < 16; ++rg) {
                    int row = rt * 32 + (rg & 3) + 8 * (rg >> 2) + 4 * hi;
                    float v = fmaxf(acc1[rt][rg] + bias, 0.f);
                    *(unsigned short*)(smem + 32768 + row * 512 +
                                       ((colq * 2) ^ ((row & 15) << 4))) = f2bf(v);
                }
        }
        __syncthreads();

        // ======== L2 partial: h1q[64x256] @ W2[q*256 .. , :] (bf16) ========
#pragma unroll 4
        for (int kk = 0; kk < 16; ++kk) {
            int kb = (kk * 16 + hi * 8) * 2;
            short8 a0 = *(const short8*)(smem + 32768 + l31 * 512 + (kb ^ swz4));
            short8 a1 = *(const short8*)(smem + 32768 + (32 + l31) * 512 + (kb ^ swz4));
#pragma unroll
            for (int c = 0; c < 2; ++c) {
                int ct = wid * 2 + c;
                short8 b = *(const short8*)(pW2 + (((size_t)ct * 64 + q * 16 + kk) * 64 + lane) * 8);
                acc2[c][0] = MFMA32B(a0, b, acc2[c][0]);
                acc2[c][1] = MFMA32B(a1, b, acc2[c][1]);
            }
        }
        __syncthreads();   // h1q reads done before next quarter overwrites it
    }

    // ======== h2 epilogue: bias+relu -> fp8 at [0,32768) (X region dead) ========
#pragma unroll
    for (int c = 0; c < 2; ++c) {
        int col = (wid * 2 + c) * 32 + l31;
        float bias = (col < 500) ? b2[col] : 0.f;
#pragma unroll
        for (int rt = 0; rt < 2; ++rt)
#pragma unroll
            for (int rg = 0; rg < 16; ++rg) {
                int row = rt * 32 + (rg & 3) + 8 * (rg >> 2) + 4 * hi;
                float v = fmaxf(acc2[c][rt][rg] + bias, 0.f);
                smem[row * 512 + (col ^ ((row & 15) << 3))] = f_to_fp8(v);
            }
    }
    __syncthreads();

    // ======== L3: h2[64x512] @ W3 (fp8) -> h3[64x256] bf16 at [32768,65536) ========
    f32x16 acc3[2];
#pragma unroll
    for (int rt = 0; rt < 2; ++rt)
#pragma unroll
        for (int rg = 0; rg < 16; ++rg) acc3[rt][rg] = 0.f;

    const unsigned long long* bp3 = pW3 + ((size_t)wid * 32) * 64 + lane;
#pragma unroll 8
    for (int kk = 0; kk < 32; ++kk) {
        int k0 = kk * 16 + hi * 8;
        long long a0 = *(const long long*)(smem + l31 * 512 + (k0 ^ swz3));
        long long a1 = *(const long long*)(smem + (32 + l31) * 512 + (k0 ^ swz3));
        long long b  = bp3[(size_t)kk * 64];
        acc3[0] = MFMA32F8(a0, b, acc3[0]);
        acc3[1] = MFMA32F8(a1, b, acc3[1]);
    }
    {
        int col = wid * 32 + l31;
        float bias = (col < 250) ? b3[col] : 0.f;
#pragma unroll
        for (int rt = 0; rt < 2; ++rt)
#pragma unroll
            for (int rg = 0; rg < 16; ++rg) {
                int row = rt * 32 + (rg & 3) + 8 * (rg >> 2) + 4 * hi;
                float v = fmaxf(acc3[rt][rg] + bias, 0.f);
                *(unsigned short*)(smem + 32768 + row * 512 +
                                   ((col * 2) ^ ((row & 15) << 4))) = f2bf(v);
            }
    }
    __syncthreads();

    // ======== L4 + loss: z = h3 . W4 + b4, 8 threads/row ========
    {
        int g  = tidx >> 3;      // row 0..63
        int t8 = tidx & 7;
        float sum = 0.f;
#pragma unroll
        for (int qq = 0; qq < 4; ++qq) {
            int colb = t8 * 32 + qq * 8;
            short8 v = *(const short8*)(smem + 32768 + g * 512 + ((colb * 2) ^ ((g & 15) << 4)));
#pragma unroll
            for (int j = 0; j < 8; ++j) {
                int cc = colb + j;
                sum += (cc < 250) ? bf2f((unsigned short)v[j]) * W4[cc] : 0.f;
            }
        }
        sum += __shfl_down(sum, 4, 8);
        sum += __shfl_down(sum, 2, 8);
        sum += __shfl_down(sum, 1, 8);
        if (t8 == 0) {
            float z = sum + b4[0];
            bool fake = (grow0 < 65536);
            float spn = softplus(-z);
            red[g]      = fake ? spn : 0.f;               // loss_F part
            red[64 + g] = fake ? softplus(z) : spn;       // loss_D part
        }
    }
    __syncthreads();
    if (tidx == 0) {
        float pF = 0.f, pD = 0.f;
        for (int i = 0; i < 64; ++i) { pF += red[i]; pD += red[64 + i]; }
        partials[(size_t)blockIdx.x * 2]     = pF;
        partials[(size_t)blockIdx.x * 2 + 1] = pD;
    }
}

// ---------------- final reduction ----------------
__global__ void reduce_partials(const float* __restrict__ partials, int nblocks,
                                float* __restrict__ out) {
    __shared__ float sF[256], sD[256];
    float f = 0.f, d = 0.f;
    for (int i = threadIdx.x; i < nblocks; i += 256) {
        f += partials[2 * i];
        d += partials[2 * i + 1];
    }
    sF[threadIdx.x] = f; sD[threadIdx.x] = d;
    __syncthreads();
    for (int s = 128; s > 0; s >>= 1) {
        if (threadIdx.x < s) {
            sF[threadIdx.x] += sF[threadIdx.x + s];
            sD[threadIdx.x] += sD[threadIdx.x + s];
        }
        __syncthreads();
    }
    if (threadIdx.x == 0) { out[0] = sF[0]; out[1] = sD[0]; }
}

extern "C" void kernel_launch(void* const* d_in, const int* in_sizes, int n_in,
                              void* d_out, int out_size, void* d_ws, size_t ws_size,
                              hipStream_t stream) {
    const float* Xf = (const float*)d_in[0];   // repr_xy_hat [65536,512]
    const float* Xr = (const float*)d_in[1];   // repr_xy     [65536,512]
    const float* W1 = (const float*)d_in[2];   // [512,1000]
    const float* b1 = (const float*)d_in[3];
    const float* W2 = (const float*)d_in[4];   // [1000,500]
    const float* b2 = (const float*)d_in[5];
    const float* W3 = (const float*)d_in[6];   // [500,250]
    const float* b3 = (const float*)d_in[7];
    const float* W4 = (const float*)d_in[8];   // [250,1]
    const float* b4 = (const float*)d_in[9];

    // ws layout:
    unsigned long long* pW1 = (unsigned long long*)d_ws;   // CT32*KT32*64 = 65536 ull (512KB)
    unsigned short* pW2 = (unsigned short*)(pW1 + 65536);  // CT16*KT64*64*8 = 524288 us (1MB)
    unsigned long long* pW3 = (unsigned long long*)(pW2 + 524288); // CT8*KT32*64 = 16384 ull (128KB)
    float* partials = (float*)(pW3 + 16384);               // 2048*2 floats (16KB)

    pack_w_fp8 <<<(32 * 32 * 64) / 256, 256, 0, stream>>>(W1, pW1, 512, 1000, 32, 32);
    pack_w_bf16<<<(16 * 64 * 64) / 256, 256, 0, stream>>>(W2, pW2, 1000, 500, 64, 16);
    pack_w_fp8 <<<(8 * 32 * 64) / 256, 256, 0, stream>>>(W3, pW3, 500, 250, 32, 8);

    fused_mlp<<<2048, 512, 0, stream>>>(Xf, Xr, pW1, pW2, pW3,
                                        b1, b2, b3, W4, b4, partials);

    reduce_partials<<<1, 256, 0, stream>>>(partials, 2048, (float*)d_out);
}

// Round 4
// 522.327 us; speedup vs baseline: 1.2960x; 1.2960x over previous
//
#include <hip/hip_runtime.h>
#include <hip/hip_bf16.h>
#include <cmath>

using short8  = __attribute__((ext_vector_type(8))) short;
using f32x16  = __attribute__((ext_vector_type(16))) float;

#define MFMA32B(a,b,c) __builtin_amdgcn_mfma_f32_32x32x16_bf16(a, b, c, 0, 0, 0)
#define MFMA32F8(a,b,c) __builtin_amdgcn_mfma_f32_32x32x16_fp8_fp8(a, b, c, 0, 0, 0)

__device__ __forceinline__ unsigned short f2bf(float f) {
    union { float f; unsigned u; } v; v.f = f;
    unsigned u = v.u;
    return (unsigned short)((u + 0x7FFFu + ((u >> 16) & 1u)) >> 16);  // RNE
}
__device__ __forceinline__ float bf2f(unsigned short h) {
    union { unsigned u; float f; } v; v.u = ((unsigned)h) << 16;
    return v.f;
}
__device__ __forceinline__ float softplus(float x) {
    return fmaxf(x, 0.f) + log1pf(expf(-fabsf(x)));  // stable
}
__device__ __forceinline__ unsigned f4_to_fp8x4(float4 f) {
    int v = __builtin_amdgcn_cvt_pk_fp8_f32(f.x, f.y, 0, false);
    v = __builtin_amdgcn_cvt_pk_fp8_f32(f.z, f.w, v, true);
    return (unsigned)v;
}
__device__ __forceinline__ unsigned char f_to_fp8(float f) {
    return (unsigned char)(__builtin_amdgcn_cvt_pk_fp8_f32(f, f, 0, false) & 0xFF);
}

// ---- bf16 B-fragment pack (32x32x16): m = ct*32+(lane&31), k = kk*16+(lane>>5)*8+j ----
__global__ void pack_w_bf16(const float* __restrict__ W, unsigned short* __restrict__ out,
                            int K_real, int M_real, int KT, int CT) {
    int tid = blockIdx.x * blockDim.x + threadIdx.x;
    if (tid >= CT * KT * 64) return;
    int lane = tid & 63;
    int t    = tid >> 6;
    int kk   = t % KT;
    int ct   = t / KT;
    int m  = ct * 32 + (lane & 31);
    int k0 = kk * 16 + ((lane >> 5) << 3);
    short8 v;
#pragma unroll
    for (int j = 0; j < 8; ++j) {
        int k = k0 + j;
        float f = (k < K_real && m < M_real) ? W[(size_t)k * M_real + m] : 0.f;
        v[j] = (short)f2bf(f);
    }
    *(((short8*)out) + tid) = v;
}

// ---- fp8 B-fragment pack (32x32x16 fp8): 8 bytes/lane, same k-map ----
__global__ void pack_w_fp8(const float* __restrict__ W, unsigned long long* __restrict__ out,
                           int K_real, int M_real, int KT, int CT) {
    int tid = blockIdx.x * blockDim.x + threadIdx.x;
    if (tid >= CT * KT * 64) return;
    int lane = tid & 63;
    int t    = tid >> 6;
    int kk   = t % KT;
    int ct   = t / KT;
    int m  = ct * 32 + (lane & 31);
    int k0 = kk * 16 + ((lane >> 5) << 3);
    float f[8];
#pragma unroll
    for (int j = 0; j < 8; ++j) {
        int k = k0 + j;
        f[j] = (k < K_real && m < M_real) ? W[(size_t)k * M_real + m] : 0.f;
    }
    unsigned lo = (unsigned)__builtin_amdgcn_cvt_pk_fp8_f32(f[0], f[1], 0, false);
    lo = (unsigned)__builtin_amdgcn_cvt_pk_fp8_f32(f[2], f[3], (int)lo, true);
    unsigned hi = (unsigned)__builtin_amdgcn_cvt_pk_fp8_f32(f[4], f[5], 0, false);
    hi = (unsigned)__builtin_amdgcn_cvt_pk_fp8_f32(f[6], f[7], (int)hi, true);
    out[tid] = (unsigned long long)lo | ((unsigned long long)hi << 32);
}

// ---------------- fused MLP + loss partials ----------------
// BM=64 rows/block, 8 waves, 2 blocks/CU (LDS 64.5KB, VGPR cap 128 via (512,2) —
// empirically the 2nd launch_bounds arg acts as blocks/CU: (512,4) forced a 64-VGPR
// cap and 675MB of spill traffic in R3; (512,2) gave VGPR=108, no spill in R2).
// LDS byte layout (region reuse over time):
//   [0,32768)     : X fp8   64x512B  (swz ^=(row&15)<<3)  -> later h2 fp8 64x512B (same swz)
//   [32768,65536) : h1q bf16 64x256col (rowBytes 512, swz ^=(row&15)<<4)
//                   -> later h3 bf16 64x256col (same layout)
// L1 (fp8) fused with L2 (bf16) in 4 col-quarter slabs of h1; acc2 persists (64 VGPR).
// L3 (fp8) -> h3 -> L4 dot + stable BCE -> per-block partials.
__global__ __launch_bounds__(512, 2) void fused_mlp(
    const float* __restrict__ Xf, const float* __restrict__ Xr,
    const unsigned long long* __restrict__ pW1, const unsigned short* __restrict__ pW2,
    const unsigned long long* __restrict__ pW3,
    const float* __restrict__ b1, const float* __restrict__ b2,
    const float* __restrict__ b3, const float* __restrict__ W4,
    const float* __restrict__ b4, float* __restrict__ partials)
{
    __shared__ __align__(16) unsigned char smem[65536];
    __shared__ float red[128];

    const int tidx = threadIdx.x;
    const int wid  = tidx >> 6;
    const int lane = tidx & 63;
    const int l31  = lane & 31;
    const int hi   = lane >> 5;
    const int swz3 = (l31 & 15) << 3;   // row-swizzle for rows l31 and 32+l31 (same &15)
    const int swz4 = (l31 & 15) << 4;

    const long grow0 = (long)blockIdx.x * 64;   // blocks 0..1023 fake, 1024..2047 real
    const float* X = (grow0 < 65536) ? (Xf + (size_t)grow0 * 512)
                                     : (Xr + (size_t)(grow0 - 65536) * 512);

    // ---- stage X (fp32 HBM -> fp8 LDS), once, full K=512 ----
    {
        float4 xr[16];
#pragma unroll
        for (int it = 0; it < 16; ++it) {
            int idx = it * 512 + tidx; int r = idx >> 7; int c4 = (idx & 127) * 4;
            xr[it] = *(const float4*)(X + (size_t)r * 512 + c4);
        }
#pragma unroll
        for (int it = 0; it < 16; ++it) {
            int idx = it * 512 + tidx; int r = idx >> 7; int c4 = (idx & 127) * 4;
            *(unsigned*)(smem + r * 512 + (c4 ^ ((r & 15) << 3))) = f4_to_fp8x4(xr[it]);
        }
    }

    f32x16 acc2[2][2];
#pragma unroll
    for (int c = 0; c < 2; ++c)
#pragma unroll
        for (int rt = 0; rt < 2; ++rt)
#pragma unroll
            for (int rg = 0; rg < 16; ++rg) acc2[c][rt][rg] = 0.f;

    __syncthreads();

    for (int q = 0; q < 4; ++q) {
        // ======== L1 quarter: X[64x512] @ W1[:, q*256 .. q*256+256) (fp8) ========
        f32x16 acc1[2];
#pragma unroll
        for (int rt = 0; rt < 2; ++rt)
#pragma unroll
            for (int rg = 0; rg < 16; ++rg) acc1[rt][rg] = 0.f;

        const int ct1 = q * 8 + wid;    // this wave's 32-col tile (global ct)
        const unsigned long long* bp1 = pW1 + ((size_t)ct1 * 32) * 64 + lane;
#pragma unroll 8
        for (int kk = 0; kk < 32; ++kk) {
            int k0 = kk * 16 + hi * 8;
            long long a0 = *(const long long*)(smem + l31 * 512 + (k0 ^ swz3));
            long long a1 = *(const long long*)(smem + (32 + l31) * 512 + (k0 ^ swz3));
            long long b  = bp1[(size_t)kk * 64];
            acc1[0] = MFMA32F8(a0, b, acc1[0]);
            acc1[1] = MFMA32F8(a1, b, acc1[1]);
        }
        // epilogue: bias+relu -> h1q bf16 at [32768,65536), local col = wid*32+l31
        {
            int colq = wid * 32 + l31;
            int colg = q * 256 + colq;
            float bias = (colg < 1000) ? b1[colg] : 0.f;
#pragma unroll
            for (int rt = 0; rt < 2; ++rt)
#pragma unroll
                for (int rg = 0; rg < 16; ++rg) {
                    int row = rt * 32 + (rg & 3) + 8 * (rg >> 2) + 4 * hi;
                    float v = fmaxf(acc1[rt][rg] + bias, 0.f);
                    *(unsigned short*)(smem + 32768 + row * 512 +
                                       ((colq * 2) ^ ((row & 15) << 4))) = f2bf(v);
                }
        }
        __syncthreads();

        // ======== L2 partial: h1q[64x256] @ W2[q*256 .. , :] (bf16) ========
#pragma unroll 4
        for (int kk = 0; kk < 16; ++kk) {
            int kb = (kk * 16 + hi * 8) * 2;
            short8 a0 = *(const short8*)(smem + 32768 + l31 * 512 + (kb ^ swz4));
            short8 a1 = *(const short8*)(smem + 32768 + (32 + l31) * 512 + (kb ^ swz4));
#pragma unroll
            for (int c = 0; c < 2; ++c) {
                int ct = wid * 2 + c;
                short8 b = *(const short8*)(pW2 + (((size_t)ct * 64 + q * 16 + kk) * 64 + lane) * 8);
                acc2[c][0] = MFMA32B(a0, b, acc2[c][0]);
                acc2[c][1] = MFMA32B(a1, b, acc2[c][1]);
            }
        }
        __syncthreads();   // h1q reads done before next quarter overwrites it
    }

    // ======== h2 epilogue: bias+relu -> fp8 at [0,32768) (X region dead) ========
#pragma unroll
    for (int c = 0; c < 2; ++c) {
        int col = (wid * 2 + c) * 32 + l31;
        float bias = (col < 500) ? b2[col] : 0.f;
#pragma unroll
        for (int rt = 0; rt < 2; ++rt)
#pragma unroll
            for (int rg = 0; rg < 16; ++rg) {
                int row = rt * 32 + (rg & 3) + 8 * (rg >> 2) + 4 * hi;
                float v = fmaxf(acc2[c][rt][rg] + bias, 0.f);
                smem[row * 512 + (col ^ ((row & 15) << 3))] = f_to_fp8(v);
            }
    }
    __syncthreads();

    // ======== L3: h2[64x512] @ W3 (fp8) -> h3[64x256] bf16 at [32768,65536) ========
    f32x16 acc3[2];
#pragma unroll
    for (int rt = 0; rt < 2; ++rt)
#pragma unroll
        for (int rg = 0; rg < 16; ++rg) acc3[rt][rg] = 0.f;

    const unsigned long long* bp3 = pW3 + ((size_t)wid * 32) * 64 + lane;
#pragma unroll 8
    for (int kk = 0; kk < 32; ++kk) {
        int k0 = kk * 16 + hi * 8;
        long long a0 = *(const long long*)(smem + l31 * 512 + (k0 ^ swz3));
        long long a1 = *(const long long*)(smem + (32 + l31) * 512 + (k0 ^ swz3));
        long long b  = bp3[(size_t)kk * 64];
        acc3[0] = MFMA32F8(a0, b, acc3[0]);
        acc3[1] = MFMA32F8(a1, b, acc3[1]);
    }
    {
        int col = wid * 32 + l31;
        float bias = (col < 250) ? b3[col] : 0.f;
#pragma unroll
        for (int rt = 0; rt < 2; ++rt)
#pragma unroll
            for (int rg = 0; rg < 16; ++rg) {
                int row = rt * 32 + (rg & 3) + 8 * (rg >> 2) + 4 * hi;
                float v = fmaxf(acc3[rt][rg] + bias, 0.f);
                *(unsigned short*)(smem + 32768 + row * 512 +
                                   ((col * 2) ^ ((row & 15) << 4))) = f2bf(v);
            }
    }
    __syncthreads();

    // ======== L4 + loss: z = h3 . W4 + b4, 8 threads/row ========
    {
        int g  = tidx >> 3;      // row 0..63
        int t8 = tidx & 7;
        float sum = 0.f;
#pragma unroll
        for (int qq = 0; qq < 4; ++qq) {
            int colb = t8 * 32 + qq * 8;
            short8 v = *(const short8*)(smem + 32768 + g * 512 + ((colb * 2) ^ ((g & 15) << 4)));
#pragma unroll
            for (int j = 0; j < 8; ++j) {
                int cc = colb + j;
                sum += (cc < 250) ? bf2f((unsigned short)v[j]) * W4[cc] : 0.f;
            }
        }
        sum += __shfl_down(sum, 4, 8);
        sum += __shfl_down(sum, 2, 8);
        sum += __shfl_down(sum, 1, 8);
        if (t8 == 0) {
            float z = sum + b4[0];
            bool fake = (grow0 < 65536);
            float spn = softplus(-z);
            red[g]      = fake ? spn : 0.f;               // loss_F part
            red[64 + g] = fake ? softplus(z) : spn;       // loss_D part
        }
    }
    __syncthreads();
    if (tidx == 0) {
        float pF = 0.f, pD = 0.f;
        for (int i = 0; i < 64; ++i) { pF += red[i]; pD += red[64 + i]; }
        partials[(size_t)blockIdx.x * 2]     = pF;
        partials[(size_t)blockIdx.x * 2 + 1] = pD;
    }
}

// ---------------- final reduction ----------------
__global__ void reduce_partials(const float* __restrict__ partials, int nblocks,
                                float* __restrict__ out) {
    __shared__ float sF[256], sD[256];
    float f = 0.f, d = 0.f;
    for (int i = threadIdx.x; i < nblocks; i += 256) {
        f += partials[2 * i];
        d += partials[2 * i + 1];
    }
    sF[threadIdx.x] = f; sD[threadIdx.x] = d;
    __syncthreads();
    for (int s = 128; s > 0; s >>= 1) {
        if (threadIdx.x < s) {
            sF[threadIdx.x] += sF[threadIdx.x + s];
            sD[threadIdx.x] += sD[threadIdx.x + s];
        }
        __syncthreads();
    }
    if (threadIdx.x == 0) { out[0] = sF[0]; out[1] = sD[0]; }
}

extern "C" void kernel_launch(void* const* d_in, const int* in_sizes, int n_in,
                              void* d_out, int out_size, void* d_ws, size_t ws_size,
                              hipStream_t stream) {
    const float* Xf = (const float*)d_in[0];   // repr_xy_hat [65536,512]
    const float* Xr = (const float*)d_in[1];   // repr_xy     [65536,512]
    const float* W1 = (const float*)d_in[2];   // [512,1000]
    const float* b1 = (const float*)d_in[3];
    const float* W2 = (const float*)d_in[4];   // [1000,500]
    const float* b2 = (const float*)d_in[5];
    const float* W3 = (const float*)d_in[6];   // [500,250]
    const float* b3 = (const float*)d_in[7];
    const float* W4 = (const float*)d_in[8];   // [250,1]
    const float* b4 = (const float*)d_in[9];

    // ws layout:
    unsigned long long* pW1 = (unsigned long long*)d_ws;   // CT32*KT32*64 = 65536 ull (512KB)
    unsigned short* pW2 = (unsigned short*)(pW1 + 65536);  // CT16*KT64*64*8 = 524288 us (1MB)
    unsigned long long* pW3 = (unsigned long long*)(pW2 + 524288); // CT8*KT32*64 = 16384 ull (128KB)
    float* partials = (float*)(pW3 + 16384);               // 2048*2 floats (16KB)

    pack_w_fp8 <<<(32 * 32 * 64) / 256, 256, 0, stream>>>(W1, pW1, 512, 1000, 32, 32);
    pack_w_bf16<<<(16 * 64 * 64) / 256, 256, 0, stream>>>(W2, pW2, 1000, 500, 64, 16);
    pack_w_fp8 <<<(8 * 32 * 64) / 256, 256, 0, stream>>>(W3, pW3, 500, 250, 32, 8);

    fused_mlp<<<2048, 512, 0, stream>>>(Xf, Xr, pW1, pW2, pW3,
                                        b1, b2, b3, W4, b4, partials);

    reduce_partials<<<1, 256, 0, stream>>>(partials, 2048, (float*)d_out);
}